// Round 20
// baseline (126.443 us; speedup 1.0000x reference)
//
#include <hip/hip_runtime.h>
#include <hip/hip_bf16.h>
#include <cstdint>
#include <cstddef>

#define I_F   1024
#define O_F   1024
#define BATCH 4096
#define KDIM  9216   // 9 * 1024 : j-major (j=0 base/swish, j=1..8 spline bases)
#define EPSC  1e-7f

typedef __bf16 bf16;
typedef __bf16 bf16x4 __attribute__((ext_vector_type(4)));
typedef __bf16 bf16x8 __attribute__((ext_vector_type(8)));
typedef float  f32x4  __attribute__((ext_vector_type(4)));

// ---------------------------------------------------------------------------
// Kernel 1 (fused prep): blocks [0,512) -> weight prep, [512,4608) -> acts.
// ---------------------------------------------------------------------------
__global__ __launch_bounds__(256) void prep_kernel(const float* __restrict__ x,
                                                   const float* __restrict__ grid,
                                                   const float* __restrict__ w,
                                                   const float* __restrict__ ss,
                                                   const float* __restrict__ bs,
                                                   bf16* __restrict__ A,
                                                   bf16* __restrict__ Wt) {
    if (blockIdx.x < 512) {
        // ---- weight prep ----
        int g = blockIdx.x * 256 + threadIdx.x;      // 131072 threads
        int i  = g & 1023;
        int o0 = (g >> 10) << 3;                     // 8 o per thread
        size_t io0 = (size_t)i * 1024 + o0;
        f32x4 ssv0 = *(const f32x4*)(ss + io0);
        f32x4 ssv1 = *(const f32x4*)(ss + io0 + 4);
        f32x4 bsv0 = *(const f32x4*)(bs + io0);
        f32x4 bsv1 = *(const f32x4*)(bs + io0 + 4);
#pragma unroll
        for (int oo = 0; oo < 8; ++oo) {
            int o = o0 + oo;
            float scale = (oo < 4) ? ssv0[oo & 3] : ssv1[oo & 3];
            float base  = (oo < 4) ? bsv0[oo & 3] : bsv1[oo & 3];
            const float* wp = w + (io0 + oo) * 8;
            f32x4 w0 = *(const f32x4*)(wp);
            f32x4 w1 = *(const f32x4*)(wp + 4);

            bf16* outp = Wt + (size_t)o * KDIM + i;
            outp[0] = (bf16)base;
#pragma unroll
            for (int k = 0; k < 4; ++k) outp[(size_t)(k + 1) * 1024] = (bf16)(w0[k] * scale);
#pragma unroll
            for (int k = 0; k < 4; ++k) outp[(size_t)(k + 5) * 1024] = (bf16)(w1[k] * scale);
        }
    } else {
        // ---- activations ----
        int t  = (blockIdx.x - 512) * 256 + threadIdx.x;  // 1,048,576 threads
        int b  = t >> 8;
        int i0 = (t & 255) << 2;
        f32x4 xv4 = *(const f32x4*)(x + (size_t)b * I_F + i0);

        float g[12];
#pragma unroll
        for (int j = 0; j < 12; ++j) g[j] = grid[j];
        float r1[11], r2[10], r3[9];
#pragma unroll
        for (int j = 0; j < 11; ++j) r1[j] = __builtin_amdgcn_rcpf(g[j + 1] - g[j] + EPSC);
#pragma unroll
        for (int j = 0; j < 10; ++j) r2[j] = __builtin_amdgcn_rcpf(g[j + 2] - g[j] + EPSC);
#pragma unroll
        for (int j = 0; j < 9;  ++j) r3[j] = __builtin_amdgcn_rcpf(g[j + 3] - g[j] + EPSC);

        float sw[4];
        float bs8[4][8];
#pragma unroll
        for (int e = 0; e < 4; ++e) {
            float xv = xv4[e];
            float bas[11];
#pragma unroll
            for (int j = 0; j < 11; ++j)
                bas[j] = (xv >= g[j] && xv < g[j + 1]) ? 1.0f : 0.0f;
#pragma unroll
            for (int j = 0; j < 10; ++j)
                bas[j] = (xv - g[j]) * r1[j] * bas[j] + (g[j + 2] - xv) * r1[j + 1] * bas[j + 1];
#pragma unroll
            for (int j = 0; j < 9; ++j)
                bas[j] = (xv - g[j]) * r2[j] * bas[j] + (g[j + 3] - xv) * r2[j + 1] * bas[j + 1];
#pragma unroll
            for (int j = 0; j < 8; ++j)
                bas[j] = (xv - g[j]) * r3[j] * bas[j] + (g[j + 4] - xv) * r3[j + 1] * bas[j + 1];
#pragma unroll
            for (int k = 0; k < 8; ++k) bs8[e][k] = bas[k];
            float sig = 1.0f / (1.0f + __expf(-xv));
            sw[e] = xv * sig;
        }

        bf16* outp = A + (size_t)b * KDIM + i0;
        *(bf16x4*)(outp) = (bf16x4){(bf16)sw[0], (bf16)sw[1], (bf16)sw[2], (bf16)sw[3]};
#pragma unroll
        for (int k = 0; k < 8; ++k)
            *(bf16x4*)(outp + (size_t)(k + 1) * 1024) =
                (bf16x4){(bf16)bs8[0][k], (bf16)bs8[1][k], (bf16)bs8[2][k], (bf16)bs8[3][k]};
    }
}

// ---------------------------------------------------------------------------
// Kernel 2: GEMM, bf16 MFMA 16x16x32, 256x256 tile, BK=64, 2x dbuf (128KB).
// R20 = R16 base + m201-style 4-phase double-barrier interleave per K-tile:
//   phase q: {ds_reads (mt-pair 2q,2q+1; ph0 also all bv) || stage issue} ->
//            barrier -> setprio(1) 16 MFMA setprio(0) -> barrier.
// Staging of tile j+1 front-loaded into phases 0 (A) and 1 (B) so tile-entry
// vmcnt(0) has >=2 phases of cover (counted-by-construction free). No asm
// lgkmcnt: compiler emits fine-grained counted waits (R6/R11 evidence).
// Slot safety: stage(j+1) targets slot (j+1)&1 = tile j-1's slot; all waves'
// tile j-1 reads completed before tile j's entry barrier. R7's confounds
// removed: conflict-free 16x16 reads, 16-MFMA chunks, no forced lgkm drain.
// ---------------------------------------------------------------------------
__device__ __forceinline__ void load_lds16(const bf16* g, bf16* l) {
    __builtin_amdgcn_global_load_lds(
        (__attribute__((address_space(1))) void*)g,
        (__attribute__((address_space(3))) void*)l, 16, 0, 0);
}

__global__ __launch_bounds__(512, 1) void gemm_kernel(const bf16* __restrict__ A,
                                                      const bf16* __restrict__ Wt,
                                                      bf16* __restrict__ parts,
                                                      int split, int ktiles) {  // BK=64 units
    __shared__ __align__(16) bf16 SA[2][16384];   // 2 slots x 32KB (256 rows x 64 k)
    __shared__ __align__(16) bf16 SB[2][16384];

    const int t    = threadIdx.x;
    const int lane = t & 63;
    const int w    = t >> 6;           // 0..7

    // XCD-chunked decode: each XCD owns a contiguous L-range sharing tn panels.
    const int nwg8 = gridDim.x >> 3;
    const int L    = (blockIdx.x & 7) * nwg8 + (blockIdx.x >> 3);
    const int nper = split << 4;
    const int tn   = L / nper;
    const int rem  = L - tn * nper;
    const int s    = rem >> 4;
    const int tm   = rem & 15;

    const int row0 = tm << 8;
    const int col0 = tn << 8;
    const size_t k0 = (size_t)s * ktiles * 64;

    // ---- staging (linear LDS dest; pre-swizzled global source) ----
    // DMA instr covers 8 rows x 8 16B-units; content(phys p, row r) = p ^ (r&7).
    const int sr8 = lane >> 3;                        // 0..7
    const int lc  = (lane & 7) ^ sr8;                 // pre-swizzled 16B-unit
    const bf16* gA0 = A  + (size_t)(row0 + w * 32 + sr8) * KDIM + k0 + lc * 8;
    const bf16* gB0 = Wt + (size_t)(col0 + w * 32 + sr8) * KDIM + k0 + lc * 8;

    // ---- fragment read coords (16x16x32, K=64 -> 2 ks slices) ----
    const int wm  = w >> 2;            // 0..1  (M half: 128 rows)
    const int wn  = w & 3;             // 0..3  (N quarter: 64 cols)
    const int r15 = lane & 15;
    const int g4  = lane >> 4;         // 0..3 k-group within a K=32 slice
    const int rx7 = r15 & 7;           // row&7

    f32x4 acc[8][4];
#pragma unroll
    for (int mt = 0; mt < 8; ++mt)
#pragma unroll
        for (int nt = 0; nt < 4; ++nt) acc[mt][nt] = (f32x4){0.f, 0.f, 0.f, 0.f};

    auto stage_A = [&](int j) {
        const int sl = j & 1;
        const bf16* pa = gA0 + (size_t)j * 64;
#pragma unroll
        for (int q = 0; q < 4; ++q)
            load_lds16(pa + (size_t)(q * 8) * KDIM, &SA[sl][(w * 32 + q * 8) * 64]);
    };
    auto stage_B = [&](int j) {
        const int sl = j & 1;
        const bf16* pb = gB0 + (size_t)j * 64;
#pragma unroll
        for (int q = 0; q < 4; ++q)
            load_lds16(pb + (size_t)(q * 8) * KDIM, &SB[sl][(w * 32 + q * 8) * 64]);
    };

    // A-fragment pair for mt = 2q, 2q+1 (both ks slices): 4 ds_read_b128.
    auto frag_a2 = [&](int sl, int q, bf16x8 (&af)[2][2]) {
#pragma unroll
        for (int m2 = 0; m2 < 2; ++m2)
#pragma unroll
            for (int ks = 0; ks < 2; ++ks)
                af[m2][ks] = *(const bf16x8*)&SA[sl][
                    (wm * 128 + (2 * q + m2) * 16 + r15) * 64
                    + (((ks * 4 + g4) ^ rx7) << 3)];
    };
    // All B fragments (shared by all 4 chunks): 8 ds_read_b128.
    auto frag_ball = [&](int sl, bf16x8 (&bv)[4][2]) {
#pragma unroll
        for (int nt = 0; nt < 4; ++nt)
#pragma unroll
            for (int ks = 0; ks < 2; ++ks)
                bv[nt][ks] = *(const bf16x8*)&SB[sl][
                    (wn * 64 + nt * 16 + r15) * 64
                    + (((ks * 4 + g4) ^ rx7) << 3)];
    };

    // 16-MFMA chunk: mt-pair (2q, 2q+1) x 4 nt x 2 ks.
    auto chunk = [&](int q, bf16x8 (&af)[2][2], bf16x8 (&bv)[4][2]) {
        __builtin_amdgcn_s_setprio(1);
#pragma unroll
        for (int ks = 0; ks < 2; ++ks)
#pragma unroll
            for (int m2 = 0; m2 < 2; ++m2)
#pragma unroll
                for (int nt = 0; nt < 4; ++nt)
                    acc[2 * q + m2][nt] = __builtin_amdgcn_mfma_f32_16x16x32_bf16(
                        af[m2][ks], bv[nt][ks], acc[2 * q + m2][nt], 0, 0, 0);
        __builtin_amdgcn_s_setprio(0);
    };

    // Prologue: tile 0 fully in flight.
    stage_A(0); stage_B(0);

    for (int j = 0; j < ktiles; ++j) {
        asm volatile("s_waitcnt vmcnt(0)" ::: "memory");   // tile j landed (>=2 phases cover)
        __builtin_amdgcn_s_barrier();                      // slot j&1 visible to all waves
        asm volatile("" ::: "memory");
        const int sl = j & 1;
        bf16x8 bv[4][2];

        // ---- phase 0: 12 reads || stage A(j+1) -> 16 MFMA (mt 0,1) ----
        {
            bf16x8 af[2][2];
            frag_ball(sl, bv);
            frag_a2(sl, 0, af);
            if (j + 1 < ktiles) stage_A(j + 1);            // slot of tile j-1 (safe)
            __builtin_amdgcn_s_barrier();
            chunk(0, af, bv);
            __builtin_amdgcn_s_barrier();
            asm volatile("" ::: "memory");
        }
        // ---- phase 1: 4 reads || stage B(j+1) -> 16 MFMA (mt 2,3) ----
        {
            bf16x8 af[2][2];
            frag_a2(sl, 1, af);
            if (j + 1 < ktiles) stage_B(j + 1);
            __builtin_amdgcn_s_barrier();
            chunk(1, af, bv);
            __builtin_amdgcn_s_barrier();
            asm volatile("" ::: "memory");
        }
        // ---- phase 2: 4 reads -> 16 MFMA (mt 4,5) ----
        {
            bf16x8 af[2][2];
            frag_a2(sl, 2, af);
            __builtin_amdgcn_s_barrier();
            chunk(2, af, bv);
            __builtin_amdgcn_s_barrier();
            asm volatile("" ::: "memory");
        }
        // ---- phase 3: 4 reads -> 16 MFMA (mt 6,7) ----
        {
            bf16x8 af[2][2];
            frag_a2(sl, 3, af);
            __builtin_amdgcn_s_barrier();
            chunk(3, af, bv);
            __builtin_amdgcn_s_barrier();
            asm volatile("" ::: "memory");
        }
    }

    // Epilogue (UNIFORM): bf16 partial for every split s.
    // 16x16 C/D layout: col = lane&15, row = (lane>>4)*4 + reg   [m89]
    bf16* cp2 = parts + (size_t)s * BATCH * O_F
              + (size_t)(row0 + wm * 128) * O_F + col0 + wn * 64 + r15;
#pragma unroll
    for (int mt = 0; mt < 8; ++mt)
#pragma unroll
        for (int nt = 0; nt < 4; ++nt)
#pragma unroll
            for (int r = 0; r < 4; ++r)
                cp2[(size_t)(mt * 16 + g4 * 4 + r) * O_F + nt * 16] = (bf16)acc[mt][nt][r];
}

// ---------------------------------------------------------------------------
// Kernel 3: out = sum(parts[0..np))   (split-K reduce), bf16 partials -> f32
// ---------------------------------------------------------------------------
__global__ __launch_bounds__(256) void add_kernel(float* __restrict__ out,
                                                  const bf16* __restrict__ parts,
                                                  int np) {
    int t = blockIdx.x * 256 + threadIdx.x;      // 1,048,576 threads, 4 f32 each
    f32x4 a = {0.f, 0.f, 0.f, 0.f};
    for (int p = 0; p < np; ++p) {
        bf16x4 b = *((const bf16x4*)(parts + (size_t)p * BATCH * O_F) + t);
#pragma unroll
        for (int e = 0; e < 4; ++e) a[e] += (float)b[e];
    }
    *((f32x4*)out + t) = a;
}

// ---------------------------------------------------------------------------
extern "C" void kernel_launch(void* const* d_in, const int* in_sizes, int n_in,
                              void* d_out, int out_size, void* d_ws, size_t ws_size,
                              hipStream_t stream) {
    const float* x    = (const float*)d_in[0];
    const float* grid = (const float*)d_in[1];
    const float* w    = (const float*)d_in[2];
    const float* ss   = (const float*)d_in[3];
    const float* bs   = (const float*)d_in[4];
    float* out = (float*)d_out;

    const size_t nA = (size_t)BATCH * KDIM * 2;   // 75.5 MB
    const size_t nW = (size_t)O_F   * KDIM * 2;   // 18.9 MB
    const size_t nP = (size_t)BATCH * O_F  * 2;   // 8.39 MB per bf16 partial

    bf16* A  = (bf16*)d_ws;
    bf16* Wt = (bf16*)((char*)d_ws + nA);
    bf16* parts = (bf16*)((char*)d_ws + nA + nW);

    prep_kernel<<<4608, 256, 0, stream>>>(x, grid, w, ss, bs, A, Wt);

    int split = (ws_size >= nA + nW + 4 * nP) ? 4
              : (ws_size >= nA + nW + 2 * nP) ? 2 : 1;
    // ktiles in BK=64 units: 9216/64 = 144 total
    gemm_kernel<<<64 * split, 512, 0, stream>>>(A, Wt, parts, split, 144 / split);
    add_kernel<<<(BATCH * O_F / 4) / 256, 256, 0, stream>>>(out, parts, split);
}

// Round 21
// 109.286 us; speedup vs baseline: 1.1570x; 1.1570x over previous
//
#include <hip/hip_runtime.h>
#include <hip/hip_bf16.h>
#include <cstdint>
#include <cstddef>

#define I_F   1024
#define O_F   1024
#define BATCH 4096
#define KDIM  9216   // 9 * 1024 : j-major (j=0 base/swish, j=1..8 spline bases)
#define EPSC  1e-7f

typedef __bf16 bf16;
typedef __bf16 bf16x4 __attribute__((ext_vector_type(4)));
typedef __bf16 bf16x8 __attribute__((ext_vector_type(8)));
typedef float  f32x4  __attribute__((ext_vector_type(4)));

// ---------------------------------------------------------------------------
// Kernel 1 (fused prep): blocks [0,512) -> weight prep, [512,4608) -> acts.
// ---------------------------------------------------------------------------
__global__ __launch_bounds__(256) void prep_kernel(const float* __restrict__ x,
                                                   const float* __restrict__ grid,
                                                   const float* __restrict__ w,
                                                   const float* __restrict__ ss,
                                                   const float* __restrict__ bs,
                                                   bf16* __restrict__ A,
                                                   bf16* __restrict__ Wt) {
    if (blockIdx.x < 512) {
        // ---- weight prep ----
        int g = blockIdx.x * 256 + threadIdx.x;      // 131072 threads
        int i  = g & 1023;
        int o0 = (g >> 10) << 3;                     // 8 o per thread
        size_t io0 = (size_t)i * 1024 + o0;
        f32x4 ssv0 = *(const f32x4*)(ss + io0);
        f32x4 ssv1 = *(const f32x4*)(ss + io0 + 4);
        f32x4 bsv0 = *(const f32x4*)(bs + io0);
        f32x4 bsv1 = *(const f32x4*)(bs + io0 + 4);
#pragma unroll
        for (int oo = 0; oo < 8; ++oo) {
            int o = o0 + oo;
            float scale = (oo < 4) ? ssv0[oo & 3] : ssv1[oo & 3];
            float base  = (oo < 4) ? bsv0[oo & 3] : bsv1[oo & 3];
            const float* wp = w + (io0 + oo) * 8;
            f32x4 w0 = *(const f32x4*)(wp);
            f32x4 w1 = *(const f32x4*)(wp + 4);

            bf16* outp = Wt + (size_t)o * KDIM + i;
            outp[0] = (bf16)base;
#pragma unroll
            for (int k = 0; k < 4; ++k) outp[(size_t)(k + 1) * 1024] = (bf16)(w0[k] * scale);
#pragma unroll
            for (int k = 0; k < 4; ++k) outp[(size_t)(k + 5) * 1024] = (bf16)(w1[k] * scale);
        }
    } else {
        // ---- activations ----
        int t  = (blockIdx.x - 512) * 256 + threadIdx.x;  // 1,048,576 threads
        int b  = t >> 8;
        int i0 = (t & 255) << 2;
        f32x4 xv4 = *(const f32x4*)(x + (size_t)b * I_F + i0);

        float g[12];
#pragma unroll
        for (int j = 0; j < 12; ++j) g[j] = grid[j];
        float r1[11], r2[10], r3[9];
#pragma unroll
        for (int j = 0; j < 11; ++j) r1[j] = __builtin_amdgcn_rcpf(g[j + 1] - g[j] + EPSC);
#pragma unroll
        for (int j = 0; j < 10; ++j) r2[j] = __builtin_amdgcn_rcpf(g[j + 2] - g[j] + EPSC);
#pragma unroll
        for (int j = 0; j < 9;  ++j) r3[j] = __builtin_amdgcn_rcpf(g[j + 3] - g[j] + EPSC);

        float sw[4];
        float bs8[4][8];
#pragma unroll
        for (int e = 0; e < 4; ++e) {
            float xv = xv4[e];
            float bas[11];
#pragma unroll
            for (int j = 0; j < 11; ++j)
                bas[j] = (xv >= g[j] && xv < g[j + 1]) ? 1.0f : 0.0f;
#pragma unroll
            for (int j = 0; j < 10; ++j)
                bas[j] = (xv - g[j]) * r1[j] * bas[j] + (g[j + 2] - xv) * r1[j + 1] * bas[j + 1];
#pragma unroll
            for (int j = 0; j < 9; ++j)
                bas[j] = (xv - g[j]) * r2[j] * bas[j] + (g[j + 3] - xv) * r2[j + 1] * bas[j + 1];
#pragma unroll
            for (int j = 0; j < 8; ++j)
                bas[j] = (xv - g[j]) * r3[j] * bas[j] + (g[j + 4] - xv) * r3[j + 1] * bas[j + 1];
#pragma unroll
            for (int k = 0; k < 8; ++k) bs8[e][k] = bas[k];
            float sig = 1.0f / (1.0f + __expf(-xv));
            sw[e] = xv * sig;
        }

        bf16* outp = A + (size_t)b * KDIM + i0;
        *(bf16x4*)(outp) = (bf16x4){(bf16)sw[0], (bf16)sw[1], (bf16)sw[2], (bf16)sw[3]};
#pragma unroll
        for (int k = 0; k < 8; ++k)
            *(bf16x4*)(outp + (size_t)(k + 1) * 1024) =
                (bf16x4){(bf16)bs8[0][k], (bf16)bs8[1][k], (bf16)bs8[2][k], (bf16)bs8[3][k]};
    }
}

// ---------------------------------------------------------------------------
// Kernel 2: GEMM  out = A(4096x9216) * Wt^T(1024x9216), bf16 MFMA 16x16x32.
// R21 = R17 verbatim (best measured: GEMM 72.3us, 1069 TF, 0 conflicts).
// BK=64 double-buffer 128KB, counted-by-construction vmcnt (loads issued one
// full tile ahead), 1 barrier/K-tile, reads-first loose schedule, setprio,
// 0-conflict swizzle pair, wave-parity slice order, XCD-chunked decode,
// uniform bf16 split-K partials.
// ---------------------------------------------------------------------------
__device__ __forceinline__ void load_lds16(const bf16* g, bf16* l) {
    __builtin_amdgcn_global_load_lds(
        (__attribute__((address_space(1))) void*)g,
        (__attribute__((address_space(3))) void*)l, 16, 0, 0);
}

__global__ __launch_bounds__(512, 1) void gemm_kernel(const bf16* __restrict__ A,
                                                      const bf16* __restrict__ Wt,
                                                      bf16* __restrict__ parts,
                                                      int split, int ktiles) {  // BK=64 units
    __shared__ __align__(16) bf16 SA[2][16384];   // 2 slots x 32KB (256 rows x 64 k)
    __shared__ __align__(16) bf16 SB[2][16384];

    const int t    = threadIdx.x;
    const int lane = t & 63;
    const int w    = t >> 6;           // 0..7

    // XCD-chunked decode: each XCD owns a contiguous L-range sharing tn panels.
    const int nwg8 = gridDim.x >> 3;
    const int L    = (blockIdx.x & 7) * nwg8 + (blockIdx.x >> 3);
    const int nper = split << 4;
    const int tn   = L / nper;
    const int rem  = L - tn * nper;
    const int s    = rem >> 4;
    const int tm   = rem & 15;

    const int row0 = tm << 8;
    const int col0 = tn << 8;
    const size_t k0 = (size_t)s * ktiles * 64;

    // ---- staging (linear LDS dest; pre-swizzled global source) ----
    // DMA instr covers 8 rows x 8 16B-units; lane l -> row +(l>>3), phys unit l&7.
    // content(phys p, row r) = logical unit p ^ (r&7)  ->  lc = (l&7) ^ (l>>3).
    const int sr8 = lane >> 3;                        // 0..7
    const int lc  = (lane & 7) ^ sr8;                 // pre-swizzled 16B-unit
    const bf16* gA0 = A  + (size_t)(row0 + w * 32 + sr8) * KDIM + k0 + lc * 8;
    const bf16* gB0 = Wt + (size_t)(col0 + w * 32 + sr8) * KDIM + k0 + lc * 8;

    // ---- fragment read coords (16x16x32, K=64 -> 2 ks slices) ----
    const int wm  = w >> 2;            // 0..1  (M half: 128 rows)
    const int wn  = w & 3;             // 0..3  (N quarter: 64 cols)
    const int r15 = lane & 15;
    const int g4  = lane >> 4;         // 0..3 k-group within a K=32 slice
    const int rx7 = r15 & 7;           // row&7 (frag bases are mult of 16)
    const int ks0 = w & 1;             // wave-parity slice order (neutral, kept)

    f32x4 acc[8][4];
#pragma unroll
    for (int mt = 0; mt < 8; ++mt)
#pragma unroll
        for (int nt = 0; nt < 4; ++nt) acc[mt][nt] = (f32x4){0.f, 0.f, 0.f, 0.f};

    auto stage = [&](int j) {
        const int sl = j & 1;
        const bf16* pa = gA0 + (size_t)j * 64;
        const bf16* pb = gB0 + (size_t)j * 64;
#pragma unroll
        for (int q = 0; q < 4; ++q)
            load_lds16(pa + (size_t)(q * 8) * KDIM, &SA[sl][(w * 32 + q * 8) * 64]);
#pragma unroll
        for (int q = 0; q < 4; ++q)
            load_lds16(pb + (size_t)(q * 8) * KDIM, &SB[sl][(w * 32 + q * 8) * 64]);
    };

    // 12 frag reads (need-order) for one K=32 slice.
    auto frag_load = [&](int sl, int ks, bf16x8 (&af)[8], bf16x8 (&bv)[4]) {
        const int cp = (((ks * 4 + g4) ^ rx7) << 3);
        af[0] = *(const bf16x8*)&SA[sl][(wm * 128 + 0 * 16 + r15) * 64 + cp];
#pragma unroll
        for (int nt = 0; nt < 4; ++nt)
            bv[nt] = *(const bf16x8*)&SB[sl][(wn * 64 + nt * 16 + r15) * 64 + cp];
#pragma unroll
        for (int mt = 1; mt < 8; ++mt)
            af[mt] = *(const bf16x8*)&SA[sl][(wm * 128 + mt * 16 + r15) * 64 + cp];
    };

    auto do_mfma = [&](bf16x8 (&af)[8], bf16x8 (&bv)[4]) {
        __builtin_amdgcn_s_setprio(1);
#pragma unroll
        for (int mt = 0; mt < 8; ++mt)
#pragma unroll
            for (int nt = 0; nt < 4; ++nt)
                acc[mt][nt] = __builtin_amdgcn_mfma_f32_16x16x32_bf16(
                    af[mt], bv[nt], acc[mt][nt], 0, 0, 0);
        __builtin_amdgcn_s_setprio(0);
    };

    // Prologue: tile 0 in flight.
    stage(0);

    for (int j = 0; j < ktiles; ++j) {
        asm volatile("s_waitcnt vmcnt(0)" ::: "memory");   // tile j landed (issued 1 tile ago)
        __builtin_amdgcn_s_barrier();                      // all waves see tile j
        asm volatile("" ::: "memory");                     // no read hoist above bar
        bf16x8 afA[8], bvA[4], afB[8], bvB[4];
        frag_load(j & 1, ks0, afA, bvA);                   // this wave's FIRST slice
        if (j + 1 < ktiles) stage(j + 1);                  // into slot read at j-1 (safe)
        do_mfma(afA, bvA);                                 // second-slice reads overlap
        frag_load(j & 1, ks0 ^ 1, afB, bvB);               // SECOND slice
        do_mfma(afB, bvB);
    }

    // Epilogue (UNIFORM): bf16 partial for every split s.
    // 16x16 C/D layout: col = lane&15, row = (lane>>4)*4 + reg   [m89]
    bf16* cp2 = parts + (size_t)s * BATCH * O_F
              + (size_t)(row0 + wm * 128) * O_F + col0 + wn * 64 + r15;
#pragma unroll
    for (int mt = 0; mt < 8; ++mt)
#pragma unroll
        for (int nt = 0; nt < 4; ++nt)
#pragma unroll
            for (int r = 0; r < 4; ++r)
                cp2[(size_t)(mt * 16 + g4 * 4 + r) * O_F + nt * 16] = (bf16)acc[mt][nt][r];
}

// ---------------------------------------------------------------------------
// Kernel 3: out = sum(parts[0..np))   (split-K reduce), bf16 partials -> f32
// ---------------------------------------------------------------------------
__global__ __launch_bounds__(256) void add_kernel(float* __restrict__ out,
                                                  const bf16* __restrict__ parts,
                                                  int np) {
    int t = blockIdx.x * 256 + threadIdx.x;      // 1,048,576 threads, 4 f32 each
    f32x4 a = {0.f, 0.f, 0.f, 0.f};
    for (int p = 0; p < np; ++p) {
        bf16x4 b = *((const bf16x4*)(parts + (size_t)p * BATCH * O_F) + t);
#pragma unroll
        for (int e = 0; e < 4; ++e) a[e] += (float)b[e];
    }
    *((f32x4*)out + t) = a;
}

// ---------------------------------------------------------------------------
extern "C" void kernel_launch(void* const* d_in, const int* in_sizes, int n_in,
                              void* d_out, int out_size, void* d_ws, size_t ws_size,
                              hipStream_t stream) {
    const float* x    = (const float*)d_in[0];
    const float* grid = (const float*)d_in[1];
    const float* w    = (const float*)d_in[2];
    const float* ss   = (const float*)d_in[3];
    const float* bs   = (const float*)d_in[4];
    float* out = (float*)d_out;

    const size_t nA = (size_t)BATCH * KDIM * 2;   // 75.5 MB
    const size_t nW = (size_t)O_F   * KDIM * 2;   // 18.9 MB
    const size_t nP = (size_t)BATCH * O_F  * 2;   // 8.39 MB per bf16 partial

    bf16* A  = (bf16*)d_ws;
    bf16* Wt = (bf16*)((char*)d_ws + nA);
    bf16* parts = (bf16*)((char*)d_ws + nA + nW);

    prep_kernel<<<4608, 256, 0, stream>>>(x, grid, w, ss, bs, A, Wt);

    int split = (ws_size >= nA + nW + 4 * nP) ? 4
              : (ws_size >= nA + nW + 2 * nP) ? 2 : 1;
    // ktiles in BK=64 units: 9216/64 = 144 total
    gemm_kernel<<<64 * split, 512, 0, stream>>>(A, Wt, parts, split, 144 / split);
    add_kernel<<<(BATCH * O_F / 4) / 256, 256, 0, stream>>>(out, parts, split);
}